// Round 8
// baseline (809.524 us; speedup 1.0000x reference)
//
#include <hip/hip_runtime.h>
#include <cstdint>
#include <cstddef>

// ---------------- common types / helpers ----------------
typedef __bf16 bf16x8 __attribute__((ext_vector_type(8)));
typedef __bf16 bf16x4 __attribute__((ext_vector_type(4)));
typedef float  f32x4  __attribute__((ext_vector_type(4)));
typedef float  f32x16 __attribute__((ext_vector_type(16)));
typedef unsigned int u32x4 __attribute__((ext_vector_type(4)));

__device__ __forceinline__ void load16_to_lds(const void* g, void* l) {
  __builtin_amdgcn_global_load_lds(
      (const __attribute__((address_space(1))) void*)g,
      (__attribute__((address_space(3))) void*)l, 16, 0, 0);
}

// pack two f32 -> one u32 of 2x bf16 (lo = a, hi = b)
__device__ __forceinline__ unsigned cvt_pk_bf16(float a, float b) {
  unsigned r;
  asm("v_cvt_pk_bf16_f32 %0, %1, %2" : "=v"(r) : "v"(a), "v"(b));
  return r;
}
// swap a[32:63] <-> b[0:31]
__device__ __forceinline__ void permlane32_swap(unsigned &a, unsigned &b) {
  asm("v_permlane32_swap_b32 %0, %1" : "+v"(a), "+v"(b));
}

// ---------------- weight cast+transpose: f32 (K,N) -> bf16 (N,K) ----------------
__global__ __launch_bounds__(256) void transpose_cast(
    const float* __restrict__ src, __bf16* __restrict__ dst, int K, int N)
{
  __shared__ float tile[32][33];
  const int n0 = blockIdx.x * 32, k0 = blockIdx.y * 32;
  const int tx = threadIdx.x, ty = threadIdx.y; // (32,8)
#pragma unroll
  for (int i = 0; i < 32; i += 8)
    tile[ty + i][tx] = src[(size_t)(k0 + ty + i) * N + n0 + tx];
  __syncthreads();
#pragma unroll
  for (int i = 0; i < 32; i += 8)
    dst[(size_t)(n0 + ty + i) * K + k0 + tx] = (__bf16)tile[tx][ty + i];
}

// 3x 1024x1024 in one launch (z picks the weight)
__global__ __launch_bounds__(256) void transpose_cast_qkv(
    const float* __restrict__ s0, const float* __restrict__ s1,
    const float* __restrict__ s2, __bf16* __restrict__ dst)
{
  __shared__ float tile[32][33];
  const float* src = blockIdx.z == 0 ? s0 : blockIdx.z == 1 ? s1 : s2;
  __bf16* d = dst + (size_t)blockIdx.z * 1024 * 1024;
  const int n0 = blockIdx.x * 32, k0 = blockIdx.y * 32;
  const int tx = threadIdx.x, ty = threadIdx.y; // (32,8)
#pragma unroll
  for (int i = 0; i < 32; i += 8)
    tile[ty + i][tx] = src[(size_t)(k0 + ty + i) * 1024 + n0 + tx];
  __syncthreads();
#pragma unroll
  for (int i = 0; i < 32; i += 8)
    d[(size_t)(n0 + ty + i) * 1024 + k0 + tx] = (__bf16)tile[tx][ty + i];
}

// ---------------- LayerNorm: f32 row(1024) -> bf16 ----------------
__global__ __launch_bounds__(256) void ln_kernel(
    const float* __restrict__ x, const float* __restrict__ g,
    const float* __restrict__ bta, __bf16* __restrict__ out)
{
  const int row = blockIdx.x;
  const int t = threadIdx.x;
  const float4 v = ((const float4*)(x + (size_t)row * 1024))[t];
  float s  = v.x + v.y + v.z + v.w;
  float ss = v.x * v.x + v.y * v.y + v.z * v.z + v.w * v.w;
#pragma unroll
  for (int o = 32; o > 0; o >>= 1) { s += __shfl_down(s, o); ss += __shfl_down(ss, o); }
  __shared__ float rs[4], rss[4];
  const int w = t >> 6, l = t & 63;
  if (l == 0) { rs[w] = s; rss[w] = ss; }
  __syncthreads();
  s  = rs[0] + rs[1] + rs[2] + rs[3];
  ss = rss[0] + rss[1] + rss[2] + rss[3];
  const float mu = s * (1.0f / 1024.0f);
  const float var = ss * (1.0f / 1024.0f) - mu * mu;
  const float rstd = rsqrtf(var + 1e-5f);
  const float4 gg = ((const float4*)g)[t];
  const float4 bb = ((const float4*)bta)[t];
  __bf16* o = out + (size_t)row * 1024 + t * 4;
  o[0] = (__bf16)((v.x - mu) * rstd * gg.x + bb.x);
  o[1] = (__bf16)((v.y - mu) * rstd * gg.y + bb.y);
  o[2] = (__bf16)((v.z - mu) * rstd * gg.z + bb.z);
  o[3] = (__bf16)((v.w - mu) * rstd * gg.w + bb.w);
}

// ---------------- bf16 MFMA GEMM: C = A(MxK) * Bt(NxK)^T ----------------
// Round-8: FULL REVERT to the round-2 structure (session-best 340.8us):
// 2-phase static-dbuf prefetch-first, KB=32 plain chunks for QKV/FC2,
// KB=64 swizzled for Wo/FC3. Every inner-loop variant since (KB=64 on all,
// bank swizzles, 256^2 tile, counted-vmcnt ring, 8-phase) measured
// neutral-to-negative on this short-K shape; K=1024 GEMMs plateau ~600 TF.
// NEW: EPI_QKV_ROPE fuses RoPE into the QKV epilogue. Pair partner of
// (row,col) is col^1 = lane l16^1 -> one __shfl_xor. Role q/k/v is
// block-uniform (col>>10). q/k write rotated values directly to qr/kr
// ([b][h][s][d], q pre-scaled 0.125*log2e for exp2-domain attn); v writes
// to qkv for v_transpose. Kills the rope_qk kernel (32MB traffic + launch).
enum { EPI_BF16 = 0, EPI_RES_F32 = 1, EPI_GELU_BF16 = 2, EPI_BIAS_RES_F32 = 3,
       EPI_QKV_ROPE = 4 };

template <int TM, int KB, int EPI>
__global__ __launch_bounds__(256, 2) void gemm_bf16(
    const __bf16* __restrict__ A, const __bf16* __restrict__ Bt,
    __bf16* __restrict__ outb, float* __restrict__ outf,
    const float* __restrict__ bias, const float* __restrict__ res,
    __bf16* __restrict__ qrp, __bf16* __restrict__ krp,
    int M, int N, int K)
{
  constexpr int MT = TM / 32;           // mt tiles per wave
  constexpr int KS = KB / 32;           // k-substeps per staged tile
  __shared__ __bf16 As0[TM * KB], As1[TM * KB];
  __shared__ __bf16 Bs0[128 * KB], Bs1[128 * KB];
  const int tid  = threadIdx.x;
  const int lane = tid & 63, w = tid >> 6;
  const int wm = w >> 1, wn = w & 1;
  const int quad = lane >> 4, l16 = lane & 15;
  const int m0 = blockIdx.y * TM, n0 = blockIdx.x * 128;

  f32x4 acc[MT][4] = {};
  const __bf16* Ag = A  + (size_t)m0 * K;
  const __bf16* Bg = Bt + (size_t)n0 * K;

#define G_STAGE(AsX, BsX, k0) {                                            \
    _Pragma("unroll")                                                      \
    for (int r2 = 0; r2 < TM * KB / 2048; ++r2) {                          \
      const int c = r2 * 256 + tid;                                        \
      const int r = c / (KB / 8), cb = c % (KB / 8);                       \
      const int g = (KB == 64) ? (cb ^ (r & 7)) : cb;                      \
      load16_to_lds(Ag + (size_t)r * K + (k0) + g * 8, &AsX[c * 8]);       \
    }                                                                      \
    _Pragma("unroll")                                                      \
    for (int r2 = 0; r2 < KB / 16; ++r2) {                                 \
      const int c = r2 * 256 + tid;                                        \
      const int r = c / (KB / 8), cb = c % (KB / 8);                       \
      const int g = (KB == 64) ? (cb ^ (r & 7)) : cb;                      \
      load16_to_lds(Bg + (size_t)r * K + (k0) + g * 8, &BsX[c * 8]);       \
    } }

#define G_COMPUTE(AsX, BsX) {                                              \
    bf16x8 af[MT][KS], bfr[4][KS];                                         \
    _Pragma("unroll")                                                      \
    for (int mt = 0; mt < MT; ++mt) {                                      \
      const int row = wm * (TM / 2) + mt * 16 + l16;                       \
      _Pragma("unroll")                                                    \
      for (int ks = 0; ks < KS; ++ks) {                                    \
        const int ch = (KB == 64) ? ((ks * 4 + quad) ^ (row & 7)) : quad;  \
        af[mt][ks] = *(const bf16x8*)&AsX[row * KB + ch * 8];              \
      }                                                                    \
    }                                                                      \
    _Pragma("unroll")                                                      \
    for (int nt = 0; nt < 4; ++nt) {                                       \
      const int row = wn * 64 + nt * 16 + l16;                             \
      _Pragma("unroll")                                                    \
      for (int ks = 0; ks < KS; ++ks) {                                    \
        const int ch = (KB == 64) ? ((ks * 4 + quad) ^ (row & 7)) : quad;  \
        bfr[nt][ks] = *(const bf16x8*)&BsX[row * KB + ch * 8];             \
      }                                                                    \
    }                                                                      \
    _Pragma("unroll")                                                      \
    for (int ks = 0; ks < KS; ++ks)                                        \
      _Pragma("unroll")                                                    \
      for (int mt = 0; mt < MT; ++mt)                                      \
        _Pragma("unroll")                                                  \
        for (int nt = 0; nt < 4; ++nt)                                     \
          acc[mt][nt] = __builtin_amdgcn_mfma_f32_16x16x32_bf16(           \
              af[mt][ks], bfr[nt][ks], acc[mt][nt], 0, 0, 0);              \
  }

  G_STAGE(As0, Bs0, 0);
  const int nk = K / KB;               // even at every call site (32/16/64)
  for (int kt = 0; kt < nk; kt += 2) {
    __syncthreads();                   // drains prefetch into buf0
    if (kt + 1 < nk) G_STAGE(As1, Bs1, (kt + 1) * KB);   // prefetch FIRST
    G_COMPUTE(As0, Bs0);
    __syncthreads();                   // drains prefetch into buf1
    if (kt + 2 < nk) G_STAGE(As0, Bs0, (kt + 2) * KB);
    G_COMPUTE(As1, Bs1);
  }
#undef G_STAGE
#undef G_COMPUTE

#pragma unroll
  for (int mt = 0; mt < MT; ++mt) {
#pragma unroll
    for (int nt = 0; nt < 4; ++nt) {
      const int col = n0 + wn * 64 + nt * 16 + l16;
#pragma unroll
      for (int i = 0; i < 4; ++i) {
        const int row = m0 + wm * (TM / 2) + mt * 16 + quad * 4 + i;
        float v = acc[mt][nt][i];
        const size_t idx = (size_t)row * N + col;
        if (EPI == EPI_BF16) {
          outb[idx] = (__bf16)v;
        } else if (EPI == EPI_RES_F32) {
          outf[idx] = v + res[idx];
        } else if (EPI == EPI_GELU_BF16) {
          v += bias[col];
          outb[idx] = (__bf16)(0.5f * v * (1.0f + erff(v * 0.70710678118f)));
        } else if (EPI == EPI_BIAS_RES_F32) {
          v += bias[col];
          outf[idx] = v + res[idx];
        } else { // EPI_QKV_ROPE
          const float vp = __shfl_xor(v, 1);     // pair partner (col^1)
          const int role = col >> 10;            // 0=q, 1=k, 2=v (block-uniform)
          if (role == 2) {
            outb[idx] = (__bf16)v;               // v -> qkv buf (for v_transpose)
          } else {
            const int s  = row & 2047, bb = row >> 11;
            const int cl = col & 1023;
            const int hh = cl >> 6, d = cl & 63, d2 = d >> 1;
            const float inv_freq =
                exp2f(-((float)d2 * (1.0f / 32.0f)) * 13.2877123795f); // log2(1e4)
            const float ang = (float)s * inv_freq;
            const float cs = cosf(ang), sn = sinf(ang);
            // out[2i] = x[2i]*c - x[2i+1]*s ; out[2i+1] = x[2i+1]*c + x[2i]*s
            const float rot = (d & 1) ? (v * cs + vp * sn) : (v * cs - vp * sn);
            const size_t o = ((size_t)(bb * 16 + hh) * 2048 + s) * 64 + d;
            if (role == 0)
              qrp[o] = (__bf16)(rot * (0.125f * 1.44269504f)); // exp2-domain
            else
              krp[o] = (__bf16)rot;
          }
        }
      }
    }
  }
}

// ---------------- V transpose: qkv v-cols -> vt [b][h][d][s] ----------------
// Pad 66 (33 words): read t[tx][ty+i] bank = tx mod 32 -> 2-way (free).
__global__ __launch_bounds__(256) void v_transpose(
    const __bf16* __restrict__ qkv, __bf16* __restrict__ vt)
{
  __shared__ __bf16 t[64][66];
  const int st = blockIdx.x, h = blockIdx.y, b = blockIdx.z;
  const int tx = threadIdx.x & 63, ty = threadIdx.x >> 6; // 64x4
  const int s0 = st * 64;
  const __bf16* src = qkv + ((size_t)(b * 2048 + s0)) * 3072 + 2048 + h * 64;
#pragma unroll
  for (int i = 0; i < 64; i += 4)
    t[ty + i][tx] = src[(size_t)(ty + i) * 3072 + tx];
  __syncthreads();
  __bf16* dst = vt + ((size_t)(b * 16 + h) * 64) * 2048 + s0;
#pragma unroll
  for (int i = 0; i < 64; i += 4)
    dst[(size_t)(ty + i) * 2048 + tx] = t[tx][ty + i];
}

// ---------------- flash attention v9: QK(t+1) / softmax(t) pipeline ---------
__global__ __launch_bounds__(256, 2) void attn_kernel(
    const __bf16* __restrict__ qr, const __bf16* __restrict__ kr,
    const __bf16* __restrict__ vt, __bf16* __restrict__ attn_o)
{
  constexpr int S = 2048, DH = 64, NH = 16, BQ = 128, BKK = 64;
  __shared__ __align__(16) __bf16 Qs[BQ * 64];           // swizzled; per-wave epilogue buf
  __shared__ __align__(16) __bf16 Ks0[64 * 64], Ks1[64 * 64], Ks2[64 * 64], Ks3[64 * 64];
  __shared__ __align__(16) __bf16 Vts0[64 * 64], Vts1[64 * 64], Vts2[64 * 64], Vts3[64 * 64];

  const int tid = threadIdx.x;
  const int lane = tid & 63, w = tid >> 6;
  const int l32 = lane & 31, half = lane >> 5;
  const int qt = blockIdx.x, h = blockIdx.y, b = blockIdx.z;
  const int bh = b * NH + h;
  const __bf16* Q  = qr + ((size_t)bh * S + qt * BQ) * DH;
  const __bf16* Kp = kr + (size_t)bh * S * DH;
  const __bf16* Vp = vt + (size_t)bh * DH * S;
  __bf16* Pb = Qs + w * 2048;                // wave-local [32][64] swizzled (epilogue only)

#define A_STAGE(KsX, VtsX, kk) {                                           \
    _Pragma("unroll")                                                      \
    for (int r2 = 0; r2 < 2; ++r2) {                                       \
      const int c = r2 * 256 + tid;                                        \
      const int r = c >> 3, cb = c & 7;                                    \
      const int cg = (cb ^ (r & 7)) * 8;                                   \
      load16_to_lds(Kp + (size_t)((kk) + r) * DH + cg, &KsX[c * 8]);       \
      load16_to_lds(Vp + (size_t)r * S + (kk) + cg, &VtsX[c * 8]);         \
    } }

  // prologue stage: Q + tiles 0,1
#pragma unroll
  for (int r4 = 0; r4 < 4; ++r4) {
    const int c = r4 * 256 + tid;
    const int r = c >> 3, cb = c & 7;
    load16_to_lds(Q + (size_t)r * DH + ((cb ^ (r & 7)) * 8), &Qs[c * 8]);
  }
  A_STAGE(Ks0, Vts0, 0);
  A_STAGE(Ks1, Vts1, BKK);
  __syncthreads();

  bf16x8 qfB[4];
  {
    const int row = w * 32 + l32;
#pragma unroll
    for (int c = 0; c < 4; ++c)
      qfB[c] = *(const bf16x8*)&Qs[row * 64 + (((2 * c + half) ^ (row & 7)) * 8)];
  }

  float mreg = -3.0e38f, lreg = 0.0f;
  f32x16 oacc[2] = {};
  const f32x16 zz = {};
  f32x16 saA[2], saB[2];

#define A_QK(KsX, saX) {                                                   \
    bf16x8 kf[2][4];                                                       \
    _Pragma("unroll")                                                      \
    for (int t = 0; t < 2; ++t) {                                          \
      const int row = 32 * t + l32;                                        \
      _Pragma("unroll")                                                    \
      for (int c = 0; c < 4; ++c)                                          \
        kf[t][c] = *(const bf16x8*)&KsX[row * 64 + (((2 * c + half) ^ (l32 & 7)) * 8)]; \
    }                                                                      \
    __builtin_amdgcn_s_setprio(1);                                         \
    _Pragma("unroll")                                                      \
    for (int t = 0; t < 2; ++t) {                                          \
      saX[t] = __builtin_amdgcn_mfma_f32_32x32x16_bf16(kf[t][0], qfB[0], zz, 0, 0, 0); \
      _Pragma("unroll")                                                    \
      for (int c = 1; c < 4; ++c)                                          \
        saX[t] = __builtin_amdgcn_mfma_f32_32x32x16_bf16(kf[t][c], qfB[c], saX[t], 0, 0, 0); \
    }                                                                      \
    __builtin_amdgcn_s_setprio(0);                                         \
  }

#define A_SMPV(saC, VtsX) {                                                \
    bf16x8 vf[2][4];                                                       \
    _Pragma("unroll")                                                      \
    for (int v = 0; v < 2; ++v) {                                          \
      const int row = 32 * v + l32;                                        \
      _Pragma("unroll")                                                    \
      for (int c = 0; c < 4; ++c)                                          \
        vf[v][c] = *(const bf16x8*)&VtsX[row * 64 + (((2 * c + half) ^ (l32 & 7)) * 8)]; \
    }                                                                      \
    float pm[8];                                                           \
    _Pragma("unroll")                                                      \
    for (int t = 0; t < 2; ++t)                                            \
      _Pragma("unroll")                                                    \
      for (int g = 0; g < 4; ++g)                                          \
        pm[t * 4 + g] = fmaxf(fmaxf(saC[t][4 * g], saC[t][4 * g + 1]),     \
                              fmaxf(saC[t][4 * g + 2], saC[t][4 * g + 3]));\
    float mx = fmaxf(fmaxf(fmaxf(pm[0], pm[1]), fmaxf(pm[2], pm[3])),      \
                     fmaxf(fmaxf(pm[4], pm[5]), fmaxf(pm[6], pm[7])));     \
    mx = fmaxf(mx, __shfl_xor(mx, 32));                                    \
    float mnew = mreg;                                                     \
    if (!__all(mx <= mreg + 8.0f)) {                                       \
      mnew = fmaxf(mreg, mx);                                              \
      const float alpha = __builtin_amdgcn_exp2f(mreg - mnew);             \
      mreg = mnew;                                                         \
      lreg *= alpha;                                                       \
      _Pragma("unroll")                                                    \
      for (int v = 0; v < 2; ++v)                                          \
        _Pragma("unroll")                                                  \
        for (int r = 0; r < 16; ++r) oacc[v][r] *= alpha;                  \
    }                                                                      \
    float ps0 = 0.f, ps1 = 0.f, ps2 = 0.f, ps3 = 0.f;                      \
    _Pragma("unroll")                                                      \
    for (int t = 0; t < 2; ++t)                                            \
      _Pragma("unroll")                                                    \
      for (int r = 0; r < 16; r += 4) {                                    \
        const float p0 = __builtin_amdgcn_exp2f(saC[t][r]     - mnew);     \
        const float p1 = __builtin_amdgcn_exp2f(saC[t][r + 1] - mnew);     \
        const float p2 = __builtin_amdgcn_exp2f(saC[t][r + 2] - mnew);     \
        const float p3 = __builtin_amdgcn_exp2f(saC[t][r + 3] - mnew);     \
        saC[t][r] = p0; saC[t][r + 1] = p1;                                \
        saC[t][r + 2] = p2; saC[t][r + 3] = p3;                            \
        ps0 += p0; ps1 += p1; ps2 += p2; ps3 += p3;                        \
      }                                                                    \
    __builtin_amdgcn_s_setprio(1);                                         \
    _Pragma("unroll")                                                      \
    for (int c = 0; c < 4; ++c) {                                          \
      const int t = c >> 1, r0 = (c & 1) * 8;                              \
      unsigned px = cvt_pk_bf16(saC[t][r0],     saC[t][r0 + 1]);           \
      unsigned py = cvt_pk_bf16(saC[t][r0 + 2], saC[t][r0 + 3]);           \
      unsigned pz = cvt_pk_bf16(saC[t][r0 + 4], saC[t][r0 + 5]);           \
      unsigned pw = cvt_pk_bf16(saC[t][r0 + 6], saC[t][r0 + 7]);           \
      permlane32_swap(px, pz);                                             \
      permlane32_swap(py, pw);                                             \
      const u32x4 pv4 = { px, py, pz, pw };                                \
      const bf16x8 pf = __builtin_bit_cast(bf16x8, pv4);                   \
      oacc[0] = __builtin_amdgcn_mfma_f32_32x32x16_bf16(vf[0][c], pf, oacc[0], 0, 0, 0); \
      oacc[1] = __builtin_amdgcn_mfma_f32_32x32x16_bf16(vf[1][c], pf, oacc[1], 0, 0, 0); \
    }                                                                      \
    __builtin_amdgcn_s_setprio(0);                                         \
    float sum = (ps0 + ps1) + (ps2 + ps3);                                 \
    sum += __shfl_xor(sum, 32);                                            \
    lreg += sum;                                                           \
  }

// phase p: barrier; stage(p+2); QK(p+1); softmax(p)+PV(p)
#define A_PHASE(KsNext, VtsCur, KsSt, VtsSt, saCur, saNext, kkSt, DO_QK, DO_ST) { \
    __syncthreads();                                                       \
    if (DO_ST) A_STAGE(KsSt, VtsSt, kkSt);                                 \
    if (DO_QK) A_QK(KsNext, saNext);                                       \
    A_SMPV(saCur, VtsCur);                                                 \
  }

  // QK(0) from Ks0 (prologue barrier already drained it)
  A_QK(Ks0, saA);

  for (int p = 0; p < 28; p += 4) {
    A_PHASE(Ks1, Vts0, Ks2, Vts2, saA, saB, (p + 2) * BKK, true, true);
    A_PHASE(Ks2, Vts1, Ks3, Vts3, saB, saA, (p + 3) * BKK, true, true);
    A_PHASE(Ks3, Vts2, Ks0, Vts0, saA, saB, (p + 4) * BKK, true, true);
    A_PHASE(Ks0, Vts3, Ks1, Vts1, saB, saA, (p + 5) * BKK, true, true);
  }
  // tail: p = 28, 29, 30, 31
  A_PHASE(Ks1, Vts0, Ks2, Vts2, saA, saB, 30 * BKK, true, true);
  A_PHASE(Ks2, Vts1, Ks3, Vts3, saB, saA, 31 * BKK, true, true);
  A_PHASE(Ks3, Vts2, Ks0, Vts0, saA, saB, 0,        true, false);
  A_PHASE(Ks0, Vts3, Ks1, Vts1, saB, saA, 0,        false, false);
#undef A_STAGE
#undef A_QK
#undef A_SMPV
#undef A_PHASE

  const float linv = 1.0f / lreg;
#pragma unroll
  for (int v = 0; v < 2; ++v)
#pragma unroll
    for (int g = 0; g < 4; ++g) {
      bf16x4 ov;
#pragma unroll
      for (int i = 0; i < 4; ++i) ov[i] = (__bf16)(oacc[v][4 * g + i] * linv);
      const int dc = 4 * v + g;
      *(bf16x4*)&Pb[l32 * 64 + ((dc ^ (l32 & 7)) * 8) + 4 * half] = ov;
    }
#pragma unroll
  for (int cc = 0; cc < 4; ++cc) {
    const int c = cc * 64 + lane;
    const int r = c >> 3, g = c & 7;
    const bf16x8 od = *(const bf16x8*)&Pb[r * 64 + ((g ^ (r & 7)) * 8)];
    const int srow = qt * BQ + w * 32 + r;
    *(bf16x8*)&attn_o[((size_t)b * S + srow) * 1024 + h * 64 + g * 8] = od;
  }
}

// ---------------- launch ----------------
extern "C" void kernel_launch(void* const* d_in, const int* in_sizes, int n_in,
                              void* d_out, int out_size, void* d_ws, size_t ws_size,
                              hipStream_t stream) {
  const float* inputs = (const float*)d_in[0];
  const float* ln1_g  = (const float*)d_in[1];
  const float* ln1_b  = (const float*)d_in[2];
  const float* Wq     = (const float*)d_in[3];
  const float* Wk     = (const float*)d_in[4];
  const float* Wv     = (const float*)d_in[5];
  const float* Wo     = (const float*)d_in[6];
  const float* ln2_g  = (const float*)d_in[7];
  const float* ln2_b  = (const float*)d_in[8];
  const float* Wfc2   = (const float*)d_in[9];
  const float* bfc2   = (const float*)d_in[10];
  const float* Wfc3   = (const float*)d_in[11];
  const float* bfc3   = (const float*)d_in[12];
  float* out = (float*)d_out;
  char* ws = (char*)d_ws;
  const size_t MB = 1024 * 1024;

  __bf16* Wqkv_t = (__bf16*)(ws);            // 6 MB: [3072][1024]
  __bf16* Wo_t   = (__bf16*)(ws + 6 * MB);   // 2 MB
  __bf16* Wfc2_t = (__bf16*)(ws + 8 * MB);   // 8 MB: [4096][1024]
  __bf16* Wfc3_t = (__bf16*)(ws + 16 * MB);  // 8 MB: [1024][4096]
  __bf16* xb     = (__bf16*)(ws + 24 * MB);  // 8 MB; reused as attn_o
  __bf16* attn_o = xb;
  __bf16* qkv    = (__bf16*)(ws + 32 * MB);  // 24 MB (v cols only used); reused:
  float*  mlp_in = (float*)(ws + 32 * MB);   //   16 MB
  __bf16* h2     = (__bf16*)(ws + 48 * MB);  //   8 MB
  __bf16* qrb    = (__bf16*)(ws + 56 * MB);  // 8 MB; qr/kr/vt reused as hbuf
  __bf16* krb    = (__bf16*)(ws + 64 * MB);
  __bf16* vtb    = (__bf16*)(ws + 72 * MB);
  __bf16* hbuf   = (__bf16*)(ws + 56 * MB);  // 32 MB (after attention)

  const dim3 tb(32, 8);
  transpose_cast_qkv<<<dim3(32, 32, 3), tb, 0, stream>>>(Wq, Wk, Wv, Wqkv_t);
  transpose_cast<<<dim3(32, 32),  tb, 0, stream>>>(Wo,   Wo_t,   1024, 1024);
  transpose_cast<<<dim3(128, 32), tb, 0, stream>>>(Wfc2, Wfc2_t, 1024, 4096);
  transpose_cast<<<dim3(32, 128), tb, 0, stream>>>(Wfc3, Wfc3_t, 4096, 1024);

  ln_kernel<<<4096, 256, 0, stream>>>(inputs, ln1_g, ln1_b, xb);

  // QKV GEMM with fused RoPE epilogue: q->qrb, k->krb (rotated), v->qkv
  gemm_bf16<128, 32, EPI_QKV_ROPE><<<dim3(24, 32), 256, 0, stream>>>(
      xb, Wqkv_t, qkv, nullptr, nullptr, nullptr, qrb, krb, 4096, 3072, 1024);

  v_transpose<<<dim3(32, 16, 2), 256, 0, stream>>>(qkv, vtb);

  attn_kernel<<<dim3(16, 16, 2), 256, 0, stream>>>(qrb, krb, vtb, attn_o);

  gemm_bf16<64, 64, EPI_RES_F32><<<dim3(8, 64), 256, 0, stream>>>(
      attn_o, Wo_t, nullptr, mlp_in, nullptr, inputs, nullptr, nullptr,
      4096, 1024, 1024);

  ln_kernel<<<4096, 256, 0, stream>>>(mlp_in, ln2_g, ln2_b, h2);

  gemm_bf16<128, 32, EPI_GELU_BF16><<<dim3(32, 32), 256, 0, stream>>>(
      h2, Wfc2_t, hbuf, nullptr, bfc2, nullptr, nullptr, nullptr,
      4096, 4096, 1024);

  gemm_bf16<64, 64, EPI_BIAS_RES_F32><<<dim3(8, 64), 256, 0, stream>>>(
      hbuf, Wfc3_t, nullptr, out, bfc3, mlp_in, nullptr, nullptr,
      4096, 1024, 4096);
}

// Round 9
// 349.130 us; speedup vs baseline: 2.3187x; 2.3187x over previous
//
#include <hip/hip_runtime.h>
#include <cstdint>
#include <cstddef>

// ---------------- common types / helpers ----------------
typedef __bf16 bf16x8 __attribute__((ext_vector_type(8)));
typedef __bf16 bf16x4 __attribute__((ext_vector_type(4)));
typedef float  f32x4  __attribute__((ext_vector_type(4)));
typedef float  f32x16 __attribute__((ext_vector_type(16)));
typedef unsigned int u32x4 __attribute__((ext_vector_type(4)));

__device__ __forceinline__ void load16_to_lds(const void* g, void* l) {
  __builtin_amdgcn_global_load_lds(
      (const __attribute__((address_space(1))) void*)g,
      (__attribute__((address_space(3))) void*)l, 16, 0, 0);
}

// pack two f32 -> one u32 of 2x bf16 (lo = a, hi = b)
__device__ __forceinline__ unsigned cvt_pk_bf16(float a, float b) {
  unsigned r;
  asm("v_cvt_pk_bf16_f32 %0, %1, %2" : "=v"(r) : "v"(a), "v"(b));
  return r;
}
// swap a[32:63] <-> b[0:31]
__device__ __forceinline__ void permlane32_swap(unsigned &a, unsigned &b) {
  asm("v_permlane32_swap_b32 %0, %1" : "+v"(a), "+v"(b));
}

// ---------------- weight cast+transpose: f32 (K,N) -> bf16 (N,K) ----------------
__global__ __launch_bounds__(256) void transpose_cast(
    const float* __restrict__ src, __bf16* __restrict__ dst, int K, int N)
{
  __shared__ float tile[32][33];
  const int n0 = blockIdx.x * 32, k0 = blockIdx.y * 32;
  const int tx = threadIdx.x, ty = threadIdx.y; // (32,8)
#pragma unroll
  for (int i = 0; i < 32; i += 8)
    tile[ty + i][tx] = src[(size_t)(k0 + ty + i) * N + n0 + tx];
  __syncthreads();
#pragma unroll
  for (int i = 0; i < 32; i += 8)
    dst[(size_t)(n0 + ty + i) * K + k0 + tx] = (__bf16)tile[tx][ty + i];
}

// 3x 1024x1024 in one launch (z picks the weight)
__global__ __launch_bounds__(256) void transpose_cast_qkv(
    const float* __restrict__ s0, const float* __restrict__ s1,
    const float* __restrict__ s2, __bf16* __restrict__ dst)
{
  __shared__ float tile[32][33];
  const float* src = blockIdx.z == 0 ? s0 : blockIdx.z == 1 ? s1 : s2;
  __bf16* d = dst + (size_t)blockIdx.z * 1024 * 1024;
  const int n0 = blockIdx.x * 32, k0 = blockIdx.y * 32;
  const int tx = threadIdx.x, ty = threadIdx.y; // (32,8)
#pragma unroll
  for (int i = 0; i < 32; i += 8)
    tile[ty + i][tx] = src[(size_t)(k0 + ty + i) * 1024 + n0 + tx];
  __syncthreads();
#pragma unroll
  for (int i = 0; i < 32; i += 8)
    d[(size_t)(n0 + ty + i) * 1024 + k0 + tx] = (__bf16)tile[tx][ty + i];
}

// ---------------- LayerNorm: f32 row(1024) -> bf16 ----------------
__global__ __launch_bounds__(256) void ln_kernel(
    const float* __restrict__ x, const float* __restrict__ g,
    const float* __restrict__ bta, __bf16* __restrict__ out)
{
  const int row = blockIdx.x;
  const int t = threadIdx.x;
  const float4 v = ((const float4*)(x + (size_t)row * 1024))[t];
  float s  = v.x + v.y + v.z + v.w;
  float ss = v.x * v.x + v.y * v.y + v.z * v.z + v.w * v.w;
#pragma unroll
  for (int o = 32; o > 0; o >>= 1) { s += __shfl_down(s, o); ss += __shfl_down(ss, o); }
  __shared__ float rs[4], rss[4];
  const int w = t >> 6, l = t & 63;
  if (l == 0) { rs[w] = s; rss[w] = ss; }
  __syncthreads();
  s  = rs[0] + rs[1] + rs[2] + rs[3];
  ss = rss[0] + rss[1] + rss[2] + rss[3];
  const float mu = s * (1.0f / 1024.0f);
  const float var = ss * (1.0f / 1024.0f) - mu * mu;
  const float rstd = rsqrtf(var + 1e-5f);
  const float4 gg = ((const float4*)g)[t];
  const float4 bb = ((const float4*)bta)[t];
  __bf16* o = out + (size_t)row * 1024 + t * 4;
  o[0] = (__bf16)((v.x - mu) * rstd * gg.x + bb.x);
  o[1] = (__bf16)((v.y - mu) * rstd * gg.y + bb.y);
  o[2] = (__bf16)((v.z - mu) * rstd * gg.z + bb.z);
  o[3] = (__bf16)((v.w - mu) * rstd * gg.w + bb.w);
}

// ---------------- bf16 MFMA GEMM: C = A(MxK) * Bt(NxK)^T ----------------
// Round-9: byte-exact restoration of the session-best config (340.8us,
// round-1 proposal). 2-phase static-dbuf prefetch-first; KB=32 plain chunks
// (QKV/FC2), KB=64 swizzled (Wo/FC3). Lessons banked from rounds 2-8:
//  - KB=32 ds_read pattern is already bank-minimal; swizzle = neutral-neg.
//  - Barrier frequency (KB=64), 256^2 tile, counted-vmcnt ring, 8-phase
//    schedule: all neutral-to-negative at K=1024 (short-K; m201 wins were
//    at K=4096).
//  - NO libm trig in epilogues with live accumulators (round-8: cosf/sinf
//    ABI calls spilled 32 acc regs to scratch -> 2.6GB HBM, 500us).
enum { EPI_BF16 = 0, EPI_RES_F32 = 1, EPI_GELU_BF16 = 2, EPI_BIAS_RES_F32 = 3 };

template <int TM, int KB, int EPI>
__global__ __launch_bounds__(256, 2) void gemm_bf16(
    const __bf16* __restrict__ A, const __bf16* __restrict__ Bt,
    __bf16* __restrict__ outb, float* __restrict__ outf,
    const float* __restrict__ bias, const float* __restrict__ res,
    int M, int N, int K)
{
  constexpr int MT = TM / 32;           // mt tiles per wave
  constexpr int KS = KB / 32;           // k-substeps per staged tile
  __shared__ __bf16 As0[TM * KB], As1[TM * KB];
  __shared__ __bf16 Bs0[128 * KB], Bs1[128 * KB];
  const int tid  = threadIdx.x;
  const int lane = tid & 63, w = tid >> 6;
  const int wm = w >> 1, wn = w & 1;
  const int quad = lane >> 4, l16 = lane & 15;
  const int m0 = blockIdx.y * TM, n0 = blockIdx.x * 128;

  f32x4 acc[MT][4] = {};
  const __bf16* Ag = A  + (size_t)m0 * K;
  const __bf16* Bg = Bt + (size_t)n0 * K;

#define G_STAGE(AsX, BsX, k0) {                                            \
    _Pragma("unroll")                                                      \
    for (int r2 = 0; r2 < TM * KB / 2048; ++r2) {                          \
      const int c = r2 * 256 + tid;                                        \
      const int r = c / (KB / 8), cb = c % (KB / 8);                       \
      const int g = (KB == 64) ? (cb ^ (r & 7)) : cb;                      \
      load16_to_lds(Ag + (size_t)r * K + (k0) + g * 8, &AsX[c * 8]);       \
    }                                                                      \
    _Pragma("unroll")                                                      \
    for (int r2 = 0; r2 < KB / 16; ++r2) {                                 \
      const int c = r2 * 256 + tid;                                        \
      const int r = c / (KB / 8), cb = c % (KB / 8);                       \
      const int g = (KB == 64) ? (cb ^ (r & 7)) : cb;                      \
      load16_to_lds(Bg + (size_t)r * K + (k0) + g * 8, &BsX[c * 8]);       \
    } }

#define G_COMPUTE(AsX, BsX) {                                              \
    bf16x8 af[MT][KS], bfr[4][KS];                                         \
    _Pragma("unroll")                                                      \
    for (int mt = 0; mt < MT; ++mt) {                                      \
      const int row = wm * (TM / 2) + mt * 16 + l16;                       \
      _Pragma("unroll")                                                    \
      for (int ks = 0; ks < KS; ++ks) {                                    \
        const int ch = (KB == 64) ? ((ks * 4 + quad) ^ (row & 7)) : quad;  \
        af[mt][ks] = *(const bf16x8*)&AsX[row * KB + ch * 8];              \
      }                                                                    \
    }                                                                      \
    _Pragma("unroll")                                                      \
    for (int nt = 0; nt < 4; ++nt) {                                       \
      const int row = wn * 64 + nt * 16 + l16;                             \
      _Pragma("unroll")                                                    \
      for (int ks = 0; ks < KS; ++ks) {                                    \
        const int ch = (KB == 64) ? ((ks * 4 + quad) ^ (row & 7)) : quad;  \
        bfr[nt][ks] = *(const bf16x8*)&BsX[row * KB + ch * 8];             \
      }                                                                    \
    }                                                                      \
    _Pragma("unroll")                                                      \
    for (int ks = 0; ks < KS; ++ks)                                        \
      _Pragma("unroll")                                                    \
      for (int mt = 0; mt < MT; ++mt)                                      \
        _Pragma("unroll")                                                  \
        for (int nt = 0; nt < 4; ++nt)                                     \
          acc[mt][nt] = __builtin_amdgcn_mfma_f32_16x16x32_bf16(           \
              af[mt][ks], bfr[nt][ks], acc[mt][nt], 0, 0, 0);              \
  }

  G_STAGE(As0, Bs0, 0);
  const int nk = K / KB;               // even at every call site (32/16/64)
  for (int kt = 0; kt < nk; kt += 2) {
    __syncthreads();                   // drains prefetch into buf0
    if (kt + 1 < nk) G_STAGE(As1, Bs1, (kt + 1) * KB);   // prefetch FIRST
    G_COMPUTE(As0, Bs0);
    __syncthreads();                   // drains prefetch into buf1
    if (kt + 2 < nk) G_STAGE(As0, Bs0, (kt + 2) * KB);
    G_COMPUTE(As1, Bs1);
  }
#undef G_STAGE
#undef G_COMPUTE

#pragma unroll
  for (int mt = 0; mt < MT; ++mt) {
#pragma unroll
    for (int nt = 0; nt < 4; ++nt) {
      const int col = n0 + wn * 64 + nt * 16 + l16;
#pragma unroll
      for (int i = 0; i < 4; ++i) {
        const int row = m0 + wm * (TM / 2) + mt * 16 + quad * 4 + i;
        float v = acc[mt][nt][i];
        const size_t idx = (size_t)row * N + col;
        if (EPI == EPI_BF16) {
          outb[idx] = (__bf16)v;
        } else if (EPI == EPI_RES_F32) {
          outf[idx] = v + res[idx];
        } else if (EPI == EPI_GELU_BF16) {
          v += bias[col];
          outb[idx] = (__bf16)(0.5f * v * (1.0f + erff(v * 0.70710678118f)));
        } else {
          v += bias[col];
          outf[idx] = v + res[idx];
        }
      }
    }
  }
}

// ---------------- RoPE for q,k: qkv(4096x3072) -> qr,kr [b][h][s][d] --------
// Q pre-scaled by 0.125*log2(e): scores land in the exp2 domain.
__global__ __launch_bounds__(256) void rope_qk(
    const __bf16* __restrict__ qkv, __bf16* __restrict__ qr, __bf16* __restrict__ kr)
{
  const int idx = blockIdx.x * 256 + threadIdx.x; // (b,s,h,d2)
  const int d2 = idx & 31;
  const int h  = (idx >> 5) & 15;
  const int bs = idx >> 9;       // b*2048+s
  const int s  = bs & 2047;
  const int b  = bs >> 11;
  const float inv_freq = exp2f(-((float)d2 * (1.0f / 32.0f)) * 13.2877123795f); // log2(1e4)
  const float ang = (float)s * inv_freq;
  const float c = cosf(ang), sn = sinf(ang);
  const float QS = 0.125f * 1.44269504f;  // (1/sqrt(64)) * log2(e)
  const __bf16* qp = qkv + (size_t)bs * 3072 + h * 64 + 2 * d2;
  const __bf16* kp = qp + 1024;
  const float q0 = (float)qp[0], q1 = (float)qp[1];
  const float k0 = (float)kp[0], k1 = (float)kp[1];
  const size_t o = ((size_t)(b * 16 + h) * 2048 + s) * 64 + 2 * d2;
  qr[o]     = (__bf16)((q0 * c - q1 * sn) * QS);
  qr[o + 1] = (__bf16)((q1 * c + q0 * sn) * QS);
  kr[o]     = (__bf16)(k0 * c - k1 * sn);
  kr[o + 1] = (__bf16)(k1 * c + k0 * sn);
}

// ---------------- V transpose: qkv v-cols -> vt [b][h][d][s] ----------------
__global__ __launch_bounds__(256) void v_transpose(
    const __bf16* __restrict__ qkv, __bf16* __restrict__ vt)
{
  __shared__ __bf16 t[64][72];
  const int st = blockIdx.x, h = blockIdx.y, b = blockIdx.z;
  const int tx = threadIdx.x & 63, ty = threadIdx.x >> 6; // 64x4
  const int s0 = st * 64;
  const __bf16* src = qkv + ((size_t)(b * 2048 + s0)) * 3072 + 2048 + h * 64;
#pragma unroll
  for (int i = 0; i < 64; i += 4)
    t[ty + i][tx] = src[(size_t)(ty + i) * 3072 + tx];
  __syncthreads();
  __bf16* dst = vt + ((size_t)(b * 16 + h) * 64) * 2048 + s0;
#pragma unroll
  for (int i = 0; i < 64; i += 4)
    dst[(size_t)(ty + i) * 2048 + tx] = t[tx][ty + i];
}

// ---------------- flash attention v9: QK(t+1) / softmax(t) pipeline ---------
// Each phase computes QK(t+1) FIRST (independent MFMA, retires under
// softmax(t) VALU), then softmax(t) -> PV(t). 4-deep static buffer rotation,
// one barrier/phase; stage(t+2) targets the buffer last read two barriers
// ago. In-register P repack (cvt_pk+permlane32_swap), defer-max THR=8,
// tree max, 4-way partial sums, setprio around MFMA clusters.
__global__ __launch_bounds__(256, 2) void attn_kernel(
    const __bf16* __restrict__ qr, const __bf16* __restrict__ kr,
    const __bf16* __restrict__ vt, __bf16* __restrict__ attn_o)
{
  constexpr int S = 2048, DH = 64, NH = 16, BQ = 128, BKK = 64;
  __shared__ __align__(16) __bf16 Qs[BQ * 64];           // swizzled; per-wave epilogue buf
  __shared__ __align__(16) __bf16 Ks0[64 * 64], Ks1[64 * 64], Ks2[64 * 64], Ks3[64 * 64];
  __shared__ __align__(16) __bf16 Vts0[64 * 64], Vts1[64 * 64], Vts2[64 * 64], Vts3[64 * 64];

  const int tid = threadIdx.x;
  const int lane = tid & 63, w = tid >> 6;
  const int l32 = lane & 31, half = lane >> 5;
  const int qt = blockIdx.x, h = blockIdx.y, b = blockIdx.z;
  const int bh = b * NH + h;
  const __bf16* Q  = qr + ((size_t)bh * S + qt * BQ) * DH;
  const __bf16* Kp = kr + (size_t)bh * S * DH;
  const __bf16* Vp = vt + (size_t)bh * DH * S;
  __bf16* Pb = Qs + w * 2048;                // wave-local [32][64] swizzled (epilogue only)

#define A_STAGE(KsX, VtsX, kk) {                                           \
    _Pragma("unroll")                                                      \
    for (int r2 = 0; r2 < 2; ++r2) {                                       \
      const int c = r2 * 256 + tid;                                        \
      const int r = c >> 3, cb = c & 7;                                    \
      const int cg = (cb ^ (r & 7)) * 8;                                   \
      load16_to_lds(Kp + (size_t)((kk) + r) * DH + cg, &KsX[c * 8]);       \
      load16_to_lds(Vp + (size_t)r * S + (kk) + cg, &VtsX[c * 8]);         \
    } }

  // prologue stage: Q + tiles 0,1
#pragma unroll
  for (int r4 = 0; r4 < 4; ++r4) {
    const int c = r4 * 256 + tid;
    const int r = c >> 3, cb = c & 7;
    load16_to_lds(Q + (size_t)r * DH + ((cb ^ (r & 7)) * 8), &Qs[c * 8]);
  }
  A_STAGE(Ks0, Vts0, 0);
  A_STAGE(Ks1, Vts1, BKK);
  __syncthreads();

  bf16x8 qfB[4];
  {
    const int row = w * 32 + l32;
#pragma unroll
    for (int c = 0; c < 4; ++c)
      qfB[c] = *(const bf16x8*)&Qs[row * 64 + (((2 * c + half) ^ (row & 7)) * 8)];
  }

  float mreg = -3.0e38f, lreg = 0.0f;
  f32x16 oacc[2] = {};
  const f32x16 zz = {};
  f32x16 saA[2], saB[2];

#define A_QK(KsX, saX) {                                                   \
    bf16x8 kf[2][4];                                                       \
    _Pragma("unroll")                                                      \
    for (int t = 0; t < 2; ++t) {                                          \
      const int row = 32 * t + l32;                                        \
      _Pragma("unroll")                                                    \
      for (int c = 0; c < 4; ++c)                                          \
        kf[t][c] = *(const bf16x8*)&KsX[row * 64 + (((2 * c + half) ^ (l32 & 7)) * 8)]; \
    }                                                                      \
    __builtin_amdgcn_s_setprio(1);                                         \
    _Pragma("unroll")                                                      \
    for (int t = 0; t < 2; ++t) {                                          \
      saX[t] = __builtin_amdgcn_mfma_f32_32x32x16_bf16(kf[t][0], qfB[0], zz, 0, 0, 0); \
      _Pragma("unroll")                                                    \
      for (int c = 1; c < 4; ++c)                                          \
        saX[t] = __builtin_amdgcn_mfma_f32_32x32x16_bf16(kf[t][c], qfB[c], saX[t], 0, 0, 0); \
    }                                                                      \
    __builtin_amdgcn_s_setprio(0);                                         \
  }

#define A_SMPV(saC, VtsX) {                                                \
    bf16x8 vf[2][4];                                                       \
    _Pragma("unroll")                                                      \
    for (int v = 0; v < 2; ++v) {                                          \
      const int row = 32 * v + l32;                                        \
      _Pragma("unroll")                                                    \
      for (int c = 0; c < 4; ++c)                                          \
        vf[v][c] = *(const bf16x8*)&VtsX[row * 64 + (((2 * c + half) ^ (l32 & 7)) * 8)]; \
    }                                                                      \
    float pm[8];                                                           \
    _Pragma("unroll")                                                      \
    for (int t = 0; t < 2; ++t)                                            \
      _Pragma("unroll")                                                    \
      for (int g = 0; g < 4; ++g)                                          \
        pm[t * 4 + g] = fmaxf(fmaxf(saC[t][4 * g], saC[t][4 * g + 1]),     \
                              fmaxf(saC[t][4 * g + 2], saC[t][4 * g + 3]));\
    float mx = fmaxf(fmaxf(fmaxf(pm[0], pm[1]), fmaxf(pm[2], pm[3])),      \
                     fmaxf(fmaxf(pm[4], pm[5]), fmaxf(pm[6], pm[7])));     \
    mx = fmaxf(mx, __shfl_xor(mx, 32));                                    \
    float mnew = mreg;                                                     \
    if (!__all(mx <= mreg + 8.0f)) {                                       \
      mnew = fmaxf(mreg, mx);                                              \
      const float alpha = __builtin_amdgcn_exp2f(mreg - mnew);             \
      mreg = mnew;                                                         \
      lreg *= alpha;                                                       \
      _Pragma("unroll")                                                    \
      for (int v = 0; v < 2; ++v)                                          \
        _Pragma("unroll")                                                  \
        for (int r = 0; r < 16; ++r) oacc[v][r] *= alpha;                  \
    }                                                                      \
    float ps0 = 0.f, ps1 = 0.f, ps2 = 0.f, ps3 = 0.f;                      \
    _Pragma("unroll")                                                      \
    for (int t = 0; t < 2; ++t)                                            \
      _Pragma("unroll")                                                    \
      for (int r = 0; r < 16; r += 4) {                                    \
        const float p0 = __builtin_amdgcn_exp2f(saC[t][r]     - mnew);     \
        const float p1 = __builtin_amdgcn_exp2f(saC[t][r + 1] - mnew);     \
        const float p2 = __builtin_amdgcn_exp2f(saC[t][r + 2] - mnew);     \
        const float p3 = __builtin_amdgcn_exp2f(saC[t][r + 3] - mnew);     \
        saC[t][r] = p0; saC[t][r + 1] = p1;                                \
        saC[t][r + 2] = p2; saC[t][r + 3] = p3;                            \
        ps0 += p0; ps1 += p1; ps2 += p2; ps3 += p3;                        \
      }                                                                    \
    __builtin_amdgcn_s_setprio(1);                                         \
    _Pragma("unroll")                                                      \
    for (int c = 0; c < 4; ++c) {                                          \
      const int t = c >> 1, r0 = (c & 1) * 8;                              \
      unsigned px = cvt_pk_bf16(saC[t][r0],     saC[t][r0 + 1]);           \
      unsigned py = cvt_pk_bf16(saC[t][r0 + 2], saC[t][r0 + 3]);           \
      unsigned pz = cvt_pk_bf16(saC[t][r0 + 4], saC[t][r0 + 5]);           \
      unsigned pw = cvt_pk_bf16(saC[t][r0 + 6], saC[t][r0 + 7]);           \
      permlane32_swap(px, pz);                                             \
      permlane32_swap(py, pw);                                             \
      const u32x4 pv4 = { px, py, pz, pw };                                \
      const bf16x8 pf = __builtin_bit_cast(bf16x8, pv4);                   \
      oacc[0] = __builtin_amdgcn_mfma_f32_32x32x16_bf16(vf[0][c], pf, oacc[0], 0, 0, 0); \
      oacc[1] = __builtin_amdgcn_mfma_f32_32x32x16_bf16(vf[1][c], pf, oacc[1], 0, 0, 0); \
    }                                                                      \
    __builtin_amdgcn_s_setprio(0);                                         \
    float sum = (ps0 + ps1) + (ps2 + ps3);                                 \
    sum += __shfl_xor(sum, 32);                                            \
    lreg += sum;                                                           \
  }

// phase p: barrier; stage(p+2); QK(p+1); softmax(p)+PV(p)
#define A_PHASE(KsNext, VtsCur, KsSt, VtsSt, saCur, saNext, kkSt, DO_QK, DO_ST) { \
    __syncthreads();                                                       \
    if (DO_ST) A_STAGE(KsSt, VtsSt, kkSt);                                 \
    if (DO_QK) A_QK(KsNext, saNext);                                       \
    A_SMPV(saCur, VtsCur);                                                 \
  }

  // QK(0) from Ks0 (prologue barrier already drained it)
  A_QK(Ks0, saA);

  for (int p = 0; p < 28; p += 4) {
    A_PHASE(Ks1, Vts0, Ks2, Vts2, saA, saB, (p + 2) * BKK, true, true);
    A_PHASE(Ks2, Vts1, Ks3, Vts3, saB, saA, (p + 3) * BKK, true, true);
    A_PHASE(Ks3, Vts2, Ks0, Vts0, saA, saB, (p + 4) * BKK, true, true);
    A_PHASE(Ks0, Vts3, Ks1, Vts1, saB, saA, (p + 5) * BKK, true, true);
  }
  // tail: p = 28, 29, 30, 31
  A_PHASE(Ks1, Vts0, Ks2, Vts2, saA, saB, 30 * BKK, true, true);
  A_PHASE(Ks2, Vts1, Ks3, Vts3, saB, saA, 31 * BKK, true, true);
  A_PHASE(Ks3, Vts2, Ks0, Vts0, saA, saB, 0,        true, false);
  A_PHASE(Ks0, Vts3, Ks1, Vts1, saB, saA, 0,        false, false);
#undef A_STAGE
#undef A_QK
#undef A_SMPV
#undef A_PHASE

  const float linv = 1.0f / lreg;
#pragma unroll
  for (int v = 0; v < 2; ++v)
#pragma unroll
    for (int g = 0; g < 4; ++g) {
      bf16x4 ov;
#pragma unroll
      for (int i = 0; i < 4; ++i) ov[i] = (__bf16)(oacc[v][4 * g + i] * linv);
      const int dc = 4 * v + g;
      *(bf16x4*)&Pb[l32 * 64 + ((dc ^ (l32 & 7)) * 8) + 4 * half] = ov;
    }
#pragma unroll
  for (int cc = 0; cc < 4; ++cc) {
    const int c = cc * 64 + lane;
    const int r = c >> 3, g = c & 7;
    const bf16x8 od = *(const bf16x8*)&Pb[r * 64 + ((g ^ (r & 7)) * 8)];
    const int srow = qt * BQ + w * 32 + r;
    *(bf16x8*)&attn_o[((size_t)b * S + srow) * 1024 + h * 64 + g * 8] = od;
  }
}

// ---------------- launch ----------------
extern "C" void kernel_launch(void* const* d_in, const int* in_sizes, int n_in,
                              void* d_out, int out_size, void* d_ws, size_t ws_size,
                              hipStream_t stream) {
  const float* inputs = (const float*)d_in[0];
  const float* ln1_g  = (const float*)d_in[1];
  const float* ln1_b  = (const float*)d_in[2];
  const float* Wq     = (const float*)d_in[3];
  const float* Wk     = (const float*)d_in[4];
  const float* Wv     = (const float*)d_in[5];
  const float* Wo     = (const float*)d_in[6];
  const float* ln2_g  = (const float*)d_in[7];
  const float* ln2_b  = (const float*)d_in[8];
  const float* Wfc2   = (const float*)d_in[9];
  const float* bfc2   = (const float*)d_in[10];
  const float* Wfc3   = (const float*)d_in[11];
  const float* bfc3   = (const float*)d_in[12];
  float* out = (float*)d_out;
  char* ws = (char*)d_ws;
  const size_t MB = 1024 * 1024;

  __bf16* Wqkv_t = (__bf16*)(ws);            // 6 MB: [3072][1024]
  __bf16* Wo_t   = (__bf16*)(ws + 6 * MB);   // 2 MB
  __bf16* Wfc2_t = (__bf16*)(ws + 8 * MB);   // 8 MB: [4096][1024]
  __bf16* Wfc3_t = (__bf16*)(ws + 16 * MB);  // 8 MB: [1024][4096]
  __bf16* xb     = (__bf16*)(ws + 24 * MB);  // 8 MB; reused as attn_o
  __bf16* attn_o = xb;
  __bf16* qkv    = (__bf16*)(ws + 32 * MB);  // 24 MB; reused:
  float*  mlp_in = (float*)(ws + 32 * MB);   //   16 MB
  __bf16* h2     = (__bf16*)(ws + 48 * MB);  //   8 MB
  __bf16* qrb    = (__bf16*)(ws + 56 * MB);  // 8 MB; qr/kr/vt reused as hbuf
  __bf16* krb    = (__bf16*)(ws + 64 * MB);
  __bf16* vtb    = (__bf16*)(ws + 72 * MB);
  __bf16* hbuf   = (__bf16*)(ws + 56 * MB);  // 32 MB (after attention)

  const dim3 tb(32, 8);
  transpose_cast_qkv<<<dim3(32, 32, 3), tb, 0, stream>>>(Wq, Wk, Wv, Wqkv_t);
  transpose_cast<<<dim3(32, 32),  tb, 0, stream>>>(Wo,   Wo_t,   1024, 1024);
  transpose_cast<<<dim3(128, 32), tb, 0, stream>>>(Wfc2, Wfc2_t, 1024, 4096);
  transpose_cast<<<dim3(32, 128), tb, 0, stream>>>(Wfc3, Wfc3_t, 4096, 1024);

  ln_kernel<<<4096, 256, 0, stream>>>(inputs, ln1_g, ln1_b, xb);

  gemm_bf16<128, 32, EPI_BF16><<<dim3(24, 32), 256, 0, stream>>>(
      xb, Wqkv_t, qkv, nullptr, nullptr, nullptr, 4096, 3072, 1024);

  rope_qk<<<8192, 256, 0, stream>>>(qkv, qrb, krb);
  v_transpose<<<dim3(32, 16, 2), 256, 0, stream>>>(qkv, vtb);

  attn_kernel<<<dim3(16, 16, 2), 256, 0, stream>>>(qrb, krb, vtb, attn_o);

  gemm_bf16<64, 64, EPI_RES_F32><<<dim3(8, 64), 256, 0, stream>>>(
      attn_o, Wo_t, nullptr, mlp_in, nullptr, inputs, 4096, 1024, 1024);

  ln_kernel<<<4096, 256, 0, stream>>>(mlp_in, ln2_g, ln2_b, h2);

  gemm_bf16<128, 32, EPI_GELU_BF16><<<dim3(32, 32), 256, 0, stream>>>(
      h2, Wfc2_t, hbuf, nullptr, bfc2, nullptr, 4096, 4096, 1024);

  gemm_bf16<64, 64, EPI_BIAS_RES_F32><<<dim3(8, 64), 256, 0, stream>>>(
      hbuf, Wfc3_t, nullptr, out, bfc3, mlp_in, 4096, 1024, 4096);
}

// Round 10
// 336.595 us; speedup vs baseline: 2.4050x; 1.0372x over previous
//
#include <hip/hip_runtime.h>
#include <cstdint>
#include <cstddef>

// ---------------- common types / helpers ----------------
typedef __bf16 bf16x8 __attribute__((ext_vector_type(8)));
typedef __bf16 bf16x4 __attribute__((ext_vector_type(4)));
typedef float  f32x4  __attribute__((ext_vector_type(4)));
typedef float  f32x16 __attribute__((ext_vector_type(16)));
typedef unsigned int u32x4 __attribute__((ext_vector_type(4)));

__device__ __forceinline__ void load16_to_lds(const void* g, void* l) {
  __builtin_amdgcn_global_load_lds(
      (const __attribute__((address_space(1))) void*)g,
      (__attribute__((address_space(3))) void*)l, 16, 0, 0);
}

// pack two f32 -> one u32 of 2x bf16 (lo = a, hi = b)
__device__ __forceinline__ unsigned cvt_pk_bf16(float a, float b) {
  unsigned r;
  asm("v_cvt_pk_bf16_f32 %0, %1, %2" : "=v"(r) : "v"(a), "v"(b));
  return r;
}
// swap a[32:63] <-> b[0:31]
__device__ __forceinline__ void permlane32_swap(unsigned &a, unsigned &b) {
  asm("v_permlane32_swap_b32 %0, %1" : "+v"(a), "+v"(b));
}

// ---------------- weight cast+transpose: f32 (K,N) -> bf16 (N,K) ----------------
__global__ __launch_bounds__(256) void transpose_cast(
    const float* __restrict__ src, __bf16* __restrict__ dst, int K, int N)
{
  __shared__ float tile[32][33];
  const int n0 = blockIdx.x * 32, k0 = blockIdx.y * 32;
  const int tx = threadIdx.x, ty = threadIdx.y; // (32,8)
#pragma unroll
  for (int i = 0; i < 32; i += 8)
    tile[ty + i][tx] = src[(size_t)(k0 + ty + i) * N + n0 + tx];
  __syncthreads();
#pragma unroll
  for (int i = 0; i < 32; i += 8)
    dst[(size_t)(n0 + ty + i) * K + k0 + tx] = (__bf16)tile[tx][ty + i];
}

// 4x 1024x1024 in one launch (z picks the weight: 0..2 -> Wqkv_t, 3 -> Wo_t)
__global__ __launch_bounds__(256) void transpose_cast_qkvo(
    const float* __restrict__ s0, const float* __restrict__ s1,
    const float* __restrict__ s2, const float* __restrict__ s3,
    __bf16* __restrict__ dqkv, __bf16* __restrict__ dwo)
{
  __shared__ float tile[32][33];
  const int z = blockIdx.z;
  const float* src = z == 0 ? s0 : z == 1 ? s1 : z == 2 ? s2 : s3;
  __bf16* d = (z < 3) ? (dqkv + (size_t)z * 1024 * 1024) : dwo;
  const int n0 = blockIdx.x * 32, k0 = blockIdx.y * 32;
  const int tx = threadIdx.x, ty = threadIdx.y; // (32,8)
#pragma unroll
  for (int i = 0; i < 32; i += 8)
    tile[ty + i][tx] = src[(size_t)(k0 + ty + i) * 1024 + n0 + tx];
  __syncthreads();
#pragma unroll
  for (int i = 0; i < 32; i += 8)
    d[(size_t)(n0 + ty + i) * 1024 + k0 + tx] = (__bf16)tile[tx][ty + i];
}

// ---------------- LayerNorm: f32 row(1024) -> bf16 ----------------
__global__ __launch_bounds__(256) void ln_kernel(
    const float* __restrict__ x, const float* __restrict__ g,
    const float* __restrict__ bta, __bf16* __restrict__ out)
{
  const int row = blockIdx.x;
  const int t = threadIdx.x;
  const float4 v = ((const float4*)(x + (size_t)row * 1024))[t];
  float s  = v.x + v.y + v.z + v.w;
  float ss = v.x * v.x + v.y * v.y + v.z * v.z + v.w * v.w;
#pragma unroll
  for (int o = 32; o > 0; o >>= 1) { s += __shfl_down(s, o); ss += __shfl_down(ss, o); }
  __shared__ float rs[4], rss[4];
  const int w = t >> 6, l = t & 63;
  if (l == 0) { rs[w] = s; rss[w] = ss; }
  __syncthreads();
  s  = rs[0] + rs[1] + rs[2] + rs[3];
  ss = rss[0] + rss[1] + rss[2] + rss[3];
  const float mu = s * (1.0f / 1024.0f);
  const float var = ss * (1.0f / 1024.0f) - mu * mu;
  const float rstd = rsqrtf(var + 1e-5f);
  const float4 gg = ((const float4*)g)[t];
  const float4 bb = ((const float4*)bta)[t];
  __bf16* o = out + (size_t)row * 1024 + t * 4;
  o[0] = (__bf16)((v.x - mu) * rstd * gg.x + bb.x);
  o[1] = (__bf16)((v.y - mu) * rstd * gg.y + bb.y);
  o[2] = (__bf16)((v.z - mu) * rstd * gg.z + bb.z);
  o[3] = (__bf16)((v.w - mu) * rstd * gg.w + bb.w);
}

// ---------------- bf16 MFMA GEMM: C = A(MxK) * Bt(NxK)^T ----------------
// Session-best structure (2-phase static-dbuf prefetch-first; KB=32 plain
// for QKV/FC2, KB=64 swizzled for Wo/FC3). Lessons banked (rounds 2-8):
//  - KB=32 ds_read is already bank-minimal; swizzle neutral-negative.
//  - Barrier freq, 256^2 tile, counted-vmcnt ring, 8-phase: all
//    neutral-to-negative at K=1024 (short-K shape).
//  - NO libm trig in epilogues with live accumulators (round-8: cosf/sinf
//    ABI calls spilled 32 acc regs -> 2.6GB scratch traffic, 500us).
// Round-10: EPI_QKV_ROPE retried with HARDWARE trig (v_sin/v_cos take
// revolutions; one fract for range reduction; all inline VALU, no calls).
// Fusion math verified correct in round-8 (passed with same absmax).
enum { EPI_BF16 = 0, EPI_RES_F32 = 1, EPI_GELU_BF16 = 2, EPI_BIAS_RES_F32 = 3,
       EPI_QKV_ROPE = 4 };

template <int TM, int KB, int EPI>
__global__ __launch_bounds__(256, 2) void gemm_bf16(
    const __bf16* __restrict__ A, const __bf16* __restrict__ Bt,
    __bf16* __restrict__ outb, float* __restrict__ outf,
    const float* __restrict__ bias, const float* __restrict__ res,
    __bf16* __restrict__ qrp, __bf16* __restrict__ krp,
    int M, int N, int K)
{
  constexpr int MT = TM / 32;           // mt tiles per wave
  constexpr int KS = KB / 32;           // k-substeps per staged tile
  __shared__ __bf16 As0[TM * KB], As1[TM * KB];
  __shared__ __bf16 Bs0[128 * KB], Bs1[128 * KB];
  const int tid  = threadIdx.x;
  const int lane = tid & 63, w = tid >> 6;
  const int wm = w >> 1, wn = w & 1;
  const int quad = lane >> 4, l16 = lane & 15;
  const int m0 = blockIdx.y * TM, n0 = blockIdx.x * 128;

  f32x4 acc[MT][4] = {};
  const __bf16* Ag = A  + (size_t)m0 * K;
  const __bf16* Bg = Bt + (size_t)n0 * K;

#define G_STAGE(AsX, BsX, k0) {                                            \
    _Pragma("unroll")                                                      \
    for (int r2 = 0; r2 < TM * KB / 2048; ++r2) {                          \
      const int c = r2 * 256 + tid;                                        \
      const int r = c / (KB / 8), cb = c % (KB / 8);                       \
      const int g = (KB == 64) ? (cb ^ (r & 7)) : cb;                      \
      load16_to_lds(Ag + (size_t)r * K + (k0) + g * 8, &AsX[c * 8]);       \
    }                                                                      \
    _Pragma("unroll")                                                      \
    for (int r2 = 0; r2 < KB / 16; ++r2) {                                 \
      const int c = r2 * 256 + tid;                                        \
      const int r = c / (KB / 8), cb = c % (KB / 8);                       \
      const int g = (KB == 64) ? (cb ^ (r & 7)) : cb;                      \
      load16_to_lds(Bg + (size_t)r * K + (k0) + g * 8, &BsX[c * 8]);       \
    } }

#define G_COMPUTE(AsX, BsX) {                                              \
    bf16x8 af[MT][KS], bfr[4][KS];                                         \
    _Pragma("unroll")                                                      \
    for (int mt = 0; mt < MT; ++mt) {                                      \
      const int row = wm * (TM / 2) + mt * 16 + l16;                       \
      _Pragma("unroll")                                                    \
      for (int ks = 0; ks < KS; ++ks) {                                    \
        const int ch = (KB == 64) ? ((ks * 4 + quad) ^ (row & 7)) : quad;  \
        af[mt][ks] = *(const bf16x8*)&AsX[row * KB + ch * 8];              \
      }                                                                    \
    }                                                                      \
    _Pragma("unroll")                                                      \
    for (int nt = 0; nt < 4; ++nt) {                                       \
      const int row = wn * 64 + nt * 16 + l16;                             \
      _Pragma("unroll")                                                    \
      for (int ks = 0; ks < KS; ++ks) {                                    \
        const int ch = (KB == 64) ? ((ks * 4 + quad) ^ (row & 7)) : quad;  \
        bfr[nt][ks] = *(const bf16x8*)&BsX[row * KB + ch * 8];             \
      }                                                                    \
    }                                                                      \
    _Pragma("unroll")                                                      \
    for (int ks = 0; ks < KS; ++ks)                                        \
      _Pragma("unroll")                                                    \
      for (int mt = 0; mt < MT; ++mt)                                      \
        _Pragma("unroll")                                                  \
        for (int nt = 0; nt < 4; ++nt)                                     \
          acc[mt][nt] = __builtin_amdgcn_mfma_f32_16x16x32_bf16(           \
              af[mt][ks], bfr[nt][ks], acc[mt][nt], 0, 0, 0);              \
  }

  G_STAGE(As0, Bs0, 0);
  const int nk = K / KB;               // even at every call site (32/16/64)
  for (int kt = 0; kt < nk; kt += 2) {
    __syncthreads();                   // drains prefetch into buf0
    if (kt + 1 < nk) G_STAGE(As1, Bs1, (kt + 1) * KB);   // prefetch FIRST
    G_COMPUTE(As0, Bs0);
    __syncthreads();                   // drains prefetch into buf1
    if (kt + 2 < nk) G_STAGE(As0, Bs0, (kt + 2) * KB);
    G_COMPUTE(As1, Bs1);
  }
#undef G_STAGE
#undef G_COMPUTE

#pragma unroll
  for (int mt = 0; mt < MT; ++mt) {
#pragma unroll
    for (int nt = 0; nt < 4; ++nt) {
      const int col = n0 + wn * 64 + nt * 16 + l16;
#pragma unroll
      for (int i = 0; i < 4; ++i) {
        const int row = m0 + wm * (TM / 2) + mt * 16 + quad * 4 + i;
        float v = acc[mt][nt][i];
        const size_t idx = (size_t)row * N + col;
        if (EPI == EPI_BF16) {
          outb[idx] = (__bf16)v;
        } else if (EPI == EPI_RES_F32) {
          outf[idx] = v + res[idx];
        } else if (EPI == EPI_GELU_BF16) {
          v += bias[col];
          outb[idx] = (__bf16)(0.5f * v * (1.0f + erff(v * 0.70710678118f)));
        } else if (EPI == EPI_BIAS_RES_F32) {
          v += bias[col];
          outf[idx] = v + res[idx];
        } else { // EPI_QKV_ROPE — hardware trig only (no libm calls!)
          const float vp = __shfl_xor(v, 1);     // pair partner (col^1)
          const int role = col >> 10;            // 0=q, 1=k, 2=v
          if (role == 2) {
            outb[idx] = (__bf16)v;               // v -> qkv buf (v_transpose)
          } else {
            const int s  = row & 2047, bb = row >> 11;
            const int cl = col & 1023;
            const int hh = cl >> 6, d = cl & 63, d2 = d >> 1;
            // revolutions: s * 10000^(-d2/32) / (2pi)
            //   = s * exp2(-d2*log2(1e4)/32 - log2(2pi))
            const float rev = (float)s * __builtin_amdgcn_exp2f(
                -((float)d2 * 0.4152410119f) - 2.6514961295f);
            const float fr = rev - floorf(rev);  // v_fract range reduction
            const float cs = __builtin_amdgcn_cosf(fr);  // v_cos_f32 (rev)
            const float sn = __builtin_amdgcn_sinf(fr);  // v_sin_f32 (rev)
            // out[2i] = x[2i]*c - x[2i+1]*s ; out[2i+1] = x[2i+1]*c + x[2i]*s
            const float rot = (d & 1) ? (v * cs + vp * sn) : (v * cs - vp * sn);
            const size_t o = ((size_t)(bb * 16 + hh) * 2048 + s) * 64 + d;
            if (role == 0)
              qrp[o] = (__bf16)(rot * (0.125f * 1.44269504f)); // exp2-domain
            else
              krp[o] = (__bf16)rot;
          }
        }
      }
    }
  }
}

// ---------------- V transpose: qkv v-cols -> vt [b][h][d][s] ----------------
__global__ __launch_bounds__(256) void v_transpose(
    const __bf16* __restrict__ qkv, __bf16* __restrict__ vt)
{
  __shared__ __bf16 t[64][72];
  const int st = blockIdx.x, h = blockIdx.y, b = blockIdx.z;
  const int tx = threadIdx.x & 63, ty = threadIdx.x >> 6; // 64x4
  const int s0 = st * 64;
  const __bf16* src = qkv + ((size_t)(b * 2048 + s0)) * 3072 + 2048 + h * 64;
#pragma unroll
  for (int i = 0; i < 64; i += 4)
    t[ty + i][tx] = src[(size_t)(ty + i) * 3072 + tx];
  __syncthreads();
  __bf16* dst = vt + ((size_t)(b * 16 + h) * 64) * 2048 + s0;
#pragma unroll
  for (int i = 0; i < 64; i += 4)
    dst[(size_t)(ty + i) * 2048 + tx] = t[tx][ty + i];
}

// ---------------- flash attention v9: QK(t+1) / softmax(t) pipeline ---------
__global__ __launch_bounds__(256, 2) void attn_kernel(
    const __bf16* __restrict__ qr, const __bf16* __restrict__ kr,
    const __bf16* __restrict__ vt, __bf16* __restrict__ attn_o)
{
  constexpr int S = 2048, DH = 64, NH = 16, BQ = 128, BKK = 64;
  __shared__ __align__(16) __bf16 Qs[BQ * 64];           // swizzled; per-wave epilogue buf
  __shared__ __align__(16) __bf16 Ks0[64 * 64], Ks1[64 * 64], Ks2[64 * 64], Ks3[64 * 64];
  __shared__ __align__(16) __bf16 Vts0[64 * 64], Vts1[64 * 64], Vts2[64 * 64], Vts3[64 * 64];

  const int tid = threadIdx.x;
  const int lane = tid & 63, w = tid >> 6;
  const int l32 = lane & 31, half = lane >> 5;
  const int qt = blockIdx.x, h = blockIdx.y, b = blockIdx.z;
  const int bh = b * NH + h;
  const __bf16* Q  = qr + ((size_t)bh * S + qt * BQ) * DH;
  const __bf16* Kp = kr + (size_t)bh * S * DH;
  const __bf16* Vp = vt + (size_t)bh * DH * S;
  __bf16* Pb = Qs + w * 2048;                // wave-local [32][64] swizzled (epilogue only)

#define A_STAGE(KsX, VtsX, kk) {                                           \
    _Pragma("unroll")                                                      \
    for (int r2 = 0; r2 < 2; ++r2) {                                       \
      const int c = r2 * 256 + tid;                                        \
      const int r = c >> 3, cb = c & 7;                                    \
      const int cg = (cb ^ (r & 7)) * 8;                                   \
      load16_to_lds(Kp + (size_t)((kk) + r) * DH + cg, &KsX[c * 8]);       \
      load16_to_lds(Vp + (size_t)r * S + (kk) + cg, &VtsX[c * 8]);         \
    } }

  // prologue stage: Q + tiles 0,1
#pragma unroll
  for (int r4 = 0; r4 < 4; ++r4) {
    const int c = r4 * 256 + tid;
    const int r = c >> 3, cb = c & 7;
    load16_to_lds(Q + (size_t)r * DH + ((cb ^ (r & 7)) * 8), &Qs[c * 8]);
  }
  A_STAGE(Ks0, Vts0, 0);
  A_STAGE(Ks1, Vts1, BKK);
  __syncthreads();

  bf16x8 qfB[4];
  {
    const int row = w * 32 + l32;
#pragma unroll
    for (int c = 0; c < 4; ++c)
      qfB[c] = *(const bf16x8*)&Qs[row * 64 + (((2 * c + half) ^ (row & 7)) * 8)];
  }

  float mreg = -3.0e38f, lreg = 0.0f;
  f32x16 oacc[2] = {};
  const f32x16 zz = {};
  f32x16 saA[2], saB[2];

#define A_QK(KsX, saX) {                                                   \
    bf16x8 kf[2][4];                                                       \
    _Pragma("unroll")                                                      \
    for (int t = 0; t < 2; ++t) {                                          \
      const int row = 32 * t + l32;                                        \
      _Pragma("unroll")                                                    \
      for (int c = 0; c < 4; ++c)                                          \
        kf[t][c] = *(const bf16x8*)&KsX[row * 64 + (((2 * c + half) ^ (l32 & 7)) * 8)]; \
    }                                                                      \
    __builtin_amdgcn_s_setprio(1);                                         \
    _Pragma("unroll")                                                      \
    for (int t = 0; t < 2; ++t) {                                          \
      saX[t] = __builtin_amdgcn_mfma_f32_32x32x16_bf16(kf[t][0], qfB[0], zz, 0, 0, 0); \
      _Pragma("unroll")                                                    \
      for (int c = 1; c < 4; ++c)                                          \
        saX[t] = __builtin_amdgcn_mfma_f32_32x32x16_bf16(kf[t][c], qfB[c], saX[t], 0, 0, 0); \
    }                                                                      \
    __builtin_amdgcn_s_setprio(0);                                         \
  }

#define A_SMPV(saC, VtsX) {                                                \
    bf16x8 vf[2][4];                                                       \
    _Pragma("unroll")                                                      \
    for (int v = 0; v < 2; ++v) {                                          \
      const int row = 32 * v + l32;                                        \
      _Pragma("unroll")                                                    \
      for (int c = 0; c < 4; ++c)                                          \
        vf[v][c] = *(const bf16x8*)&VtsX[row * 64 + (((2 * c + half) ^ (l32 & 7)) * 8)]; \
    }                                                                      \
    float pm[8];                                                           \
    _Pragma("unroll")                                                      \
    for (int t = 0; t < 2; ++t)                                            \
      _Pragma("unroll")                                                    \
      for (int g = 0; g < 4; ++g)                                          \
        pm[t * 4 + g] = fmaxf(fmaxf(saC[t][4 * g], saC[t][4 * g + 1]),     \
                              fmaxf(saC[t][4 * g + 2], saC[t][4 * g + 3]));\
    float mx = fmaxf(fmaxf(fmaxf(pm[0], pm[1]), fmaxf(pm[2], pm[3])),      \
                     fmaxf(fmaxf(pm[4], pm[5]), fmaxf(pm[6], pm[7])));     \
    mx = fmaxf(mx, __shfl_xor(mx, 32));                                    \
    float mnew = mreg;                                                     \
    if (!__all(mx <= mreg + 8.0f)) {                                       \
      mnew = fmaxf(mreg, mx);                                              \
      const float alpha = __builtin_amdgcn_exp2f(mreg - mnew);             \
      mreg = mnew;                                                         \
      lreg *= alpha;                                                       \
      _Pragma("unroll")                                                    \
      for (int v = 0; v < 2; ++v)                                          \
        _Pragma("unroll")                                                  \
        for (int r = 0; r < 16; ++r) oacc[v][r] *= alpha;                  \
    }                                                                      \
    float ps0 = 0.f, ps1 = 0.f, ps2 = 0.f, ps3 = 0.f;                      \
    _Pragma("unroll")                                                      \
    for (int t = 0; t < 2; ++t)                                            \
      _Pragma("unroll")                                                    \
      for (int r = 0; r < 16; r += 4) {                                    \
        const float p0 = __builtin_amdgcn_exp2f(saC[t][r]     - mnew);     \
        const float p1 = __builtin_amdgcn_exp2f(saC[t][r + 1] - mnew);     \
        const float p2 = __builtin_amdgcn_exp2f(saC[t][r + 2] - mnew);     \
        const float p3 = __builtin_amdgcn_exp2f(saC[t][r + 3] - mnew);     \
        saC[t][r] = p0; saC[t][r + 1] = p1;                                \
        saC[t][r + 2] = p2; saC[t][r + 3] = p3;                            \
        ps0 += p0; ps1 += p1; ps2 += p2; ps3 += p3;                        \
      }                                                                    \
    __builtin_amdgcn_s_setprio(1);                                         \
    _Pragma("unroll")                                                      \
    for (int c = 0; c < 4; ++c) {                                          \
      const int t = c >> 1, r0 = (c & 1) * 8;                              \
      unsigned px = cvt_pk_bf16(saC[t][r0],     saC[t][r0 + 1]);           \
      unsigned py = cvt_pk_bf16(saC[t][r0 + 2], saC[t][r0 + 3]);           \
      unsigned pz = cvt_pk_bf16(saC[t][r0 + 4], saC[t][r0 + 5]);           \
      unsigned pw = cvt_pk_bf16(saC[t][r0 + 6], saC[t][r0 + 7]);           \
      permlane32_swap(px, pz);                                             \
      permlane32_swap(py, pw);                                             \
      const u32x4 pv4 = { px, py, pz, pw };                                \
      const bf16x8 pf = __builtin_bit_cast(bf16x8, pv4);                   \
      oacc[0] = __builtin_amdgcn_mfma_f32_32x32x16_bf16(vf[0][c], pf, oacc[0], 0, 0, 0); \
      oacc[1] = __builtin_amdgcn_mfma_f32_32x32x16_bf16(vf[1][c], pf, oacc[1], 0, 0, 0); \
    }                                                                      \
    __builtin_amdgcn_s_setprio(0);                                         \
    float sum = (ps0 + ps1) + (ps2 + ps3);                                 \
    sum += __shfl_xor(sum, 32);                                            \
    lreg += sum;                                                           \
  }

// phase p: barrier; stage(p+2); QK(p+1); softmax(p)+PV(p)
#define A_PHASE(KsNext, VtsCur, KsSt, VtsSt, saCur, saNext, kkSt, DO_QK, DO_ST) { \
    __syncthreads();                                                       \
    if (DO_ST) A_STAGE(KsSt, VtsSt, kkSt);                                 \
    if (DO_QK) A_QK(KsNext, saNext);                                       \
    A_SMPV(saCur, VtsCur);                                                 \
  }

  // QK(0) from Ks0 (prologue barrier already drained it)
  A_QK(Ks0, saA);

  for (int p = 0; p < 28; p += 4) {
    A_PHASE(Ks1, Vts0, Ks2, Vts2, saA, saB, (p + 2) * BKK, true, true);
    A_PHASE(Ks2, Vts1, Ks3, Vts3, saB, saA, (p + 3) * BKK, true, true);
    A_PHASE(Ks3, Vts2, Ks0, Vts0, saA, saB, (p + 4) * BKK, true, true);
    A_PHASE(Ks0, Vts3, Ks1, Vts1, saB, saA, (p + 5) * BKK, true, true);
  }
  // tail: p = 28, 29, 30, 31
  A_PHASE(Ks1, Vts0, Ks2, Vts2, saA, saB, 30 * BKK, true, true);
  A_PHASE(Ks2, Vts1, Ks3, Vts3, saB, saA, 31 * BKK, true, true);
  A_PHASE(Ks3, Vts2, Ks0, Vts0, saA, saB, 0,        true, false);
  A_PHASE(Ks0, Vts3, Ks1, Vts1, saB, saA, 0,        false, false);
#undef A_STAGE
#undef A_QK
#undef A_SMPV
#undef A_PHASE

  const float linv = 1.0f / lreg;
#pragma unroll
  for (int v = 0; v < 2; ++v)
#pragma unroll
    for (int g = 0; g < 4; ++g) {
      bf16x4 ov;
#pragma unroll
      for (int i = 0; i < 4; ++i) ov[i] = (__bf16)(oacc[v][4 * g + i] * linv);
      const int dc = 4 * v + g;
      *(bf16x4*)&Pb[l32 * 64 + ((dc ^ (l32 & 7)) * 8) + 4 * half] = ov;
    }
#pragma unroll
  for (int cc = 0; cc < 4; ++cc) {
    const int c = cc * 64 + lane;
    const int r = c >> 3, g = c & 7;
    const bf16x8 od = *(const bf16x8*)&Pb[r * 64 + ((g ^ (r & 7)) * 8)];
    const int srow = qt * BQ + w * 32 + r;
    *(bf16x8*)&attn_o[((size_t)b * S + srow) * 1024 + h * 64 + g * 8] = od;
  }
}

// ---------------- launch ----------------
extern "C" void kernel_launch(void* const* d_in, const int* in_sizes, int n_in,
                              void* d_out, int out_size, void* d_ws, size_t ws_size,
                              hipStream_t stream) {
  const float* inputs = (const float*)d_in[0];
  const float* ln1_g  = (const float*)d_in[1];
  const float* ln1_b  = (const float*)d_in[2];
  const float* Wq     = (const float*)d_in[3];
  const float* Wk     = (const float*)d_in[4];
  const float* Wv     = (const float*)d_in[5];
  const float* Wo     = (const float*)d_in[6];
  const float* ln2_g  = (const float*)d_in[7];
  const float* ln2_b  = (const float*)d_in[8];
  const float* Wfc2   = (const float*)d_in[9];
  const float* bfc2   = (const float*)d_in[10];
  const float* Wfc3   = (const float*)d_in[11];
  const float* bfc3   = (const float*)d_in[12];
  float* out = (float*)d_out;
  char* ws = (char*)d_ws;
  const size_t MB = 1024 * 1024;

  __bf16* Wqkv_t = (__bf16*)(ws);            // 6 MB: [3072][1024]
  __bf16* Wo_t   = (__bf16*)(ws + 6 * MB);   // 2 MB
  __bf16* Wfc2_t = (__bf16*)(ws + 8 * MB);   // 8 MB: [4096][1024]
  __bf16* Wfc3_t = (__bf16*)(ws + 16 * MB);  // 8 MB: [1024][4096]
  __bf16* xb     = (__bf16*)(ws + 24 * MB);  // 8 MB; reused as attn_o
  __bf16* attn_o = xb;
  __bf16* qkv    = (__bf16*)(ws + 32 * MB);  // 24 MB (v cols used); reused:
  float*  mlp_in = (float*)(ws + 32 * MB);   //   16 MB
  __bf16* h2     = (__bf16*)(ws + 48 * MB);  //   8 MB
  __bf16* qrb    = (__bf16*)(ws + 56 * MB);  // 8 MB; qr/kr/vt reused as hbuf
  __bf16* krb    = (__bf16*)(ws + 64 * MB);
  __bf16* vtb    = (__bf16*)(ws + 72 * MB);
  __bf16* hbuf   = (__bf16*)(ws + 56 * MB);  // 32 MB (after attention)

  const dim3 tb(32, 8);
  transpose_cast_qkvo<<<dim3(32, 32, 4), tb, 0, stream>>>(
      Wq, Wk, Wv, Wo, Wqkv_t, Wo_t);
  transpose_cast<<<dim3(128, 32), tb, 0, stream>>>(Wfc2, Wfc2_t, 1024, 4096);
  transpose_cast<<<dim3(32, 128), tb, 0, stream>>>(Wfc3, Wfc3_t, 4096, 1024);

  ln_kernel<<<4096, 256, 0, stream>>>(inputs, ln1_g, ln1_b, xb);

  // QKV GEMM with fused RoPE epilogue (hardware trig): q->qrb, k->krb, v->qkv
  gemm_bf16<128, 32, EPI_QKV_ROPE><<<dim3(24, 32), 256, 0, stream>>>(
      xb, Wqkv_t, qkv, nullptr, nullptr, nullptr, qrb, krb, 4096, 3072, 1024);

  v_transpose<<<dim3(32, 16, 2), 256, 0, stream>>>(qkv, vtb);

  attn_kernel<<<dim3(16, 16, 2), 256, 0, stream>>>(qrb, krb, vtb, attn_o);

  gemm_bf16<64, 64, EPI_RES_F32><<<dim3(8, 64), 256, 0, stream>>>(
      attn_o, Wo_t, nullptr, mlp_in, nullptr, inputs, nullptr, nullptr,
      4096, 1024, 1024);

  ln_kernel<<<4096, 256, 0, stream>>>(mlp_in, ln2_g, ln2_b, h2);

  gemm_bf16<128, 32, EPI_GELU_BF16><<<dim3(32, 32), 256, 0, stream>>>(
      h2, Wfc2_t, hbuf, nullptr, bfc2, nullptr, nullptr, nullptr,
      4096, 4096, 1024);

  gemm_bf16<64, 64, EPI_BIAS_RES_F32><<<dim3(8, 64), 256, 0, stream>>>(
      hbuf, Wfc3_t, nullptr, out, bfc3, mlp_in, nullptr, nullptr,
      4096, 1024, 4096);
}